// Round 7
// baseline (141.242 us; speedup 1.0000x reference)
//
#include <hip/hip_runtime.h>
#include <hip/hip_bf16.h>

// B=16384 rows of logits[B,4096]; prototypes[4096,768]; boundaries[4096]
#define NB 16384
#define NC 4096
#define ND 768
#define NT64 64            // 4096/64 tiles per dim
#define NIC64 2080         // 64*65/2 upper-triangle tile pairs
#define CEB 2048           // CE blocks: 8 rows each (2 per wave)
#define GRID 4128          // 2*2048 interleaved + 32 extra IC

// ws: [0) double nllp[2048]; [16384) float icp[2080]   (all fully rewritten
// every call; no memset needed, no atomics anywhere)
#define WS_ICP 16384

// LESSON (R2/R3): fat fusion (128-tile IC + 64-VGPR CE cache) -> 156 VGPR +
//   scratch spills -> 11-19x loss. Fusion needs BOTH roles lean.
// LESSON (R6): same-address double atomics (2048 on one cache line) + memset
//   fill nodes cost ~20us. Partial arrays + separate tiny reduce instead.
// LESSON (R4/R5): CE shape and IC tile count don't move the total ->
//   the remaining win is overlap, not per-kernel tuning.

typedef __bf16 bf16x8 __attribute__((ext_vector_type(8)));
typedef float  f32x4  __attribute__((ext_vector_type(4)));

__device__ __forceinline__ unsigned short f2bf(float f) {
    return __builtin_bit_cast(unsigned short, __float2bfloat16(f));
}

// One kernel, two lean roles, interleaved so each CU hosts a mix:
//  even blockIdx (first 4096): CE rows  | odd blockIdx + tail: IC tiles.
__global__ __launch_bounds__(256) void fused_kernel(
    const float* __restrict__ logits, const int* __restrict__ targets,
    const float* __restrict__ prot, const float* __restrict__ bnd,
    double* __restrict__ nllp, float* __restrict__ icp)
{
    __shared__ __bf16 As[64][72];    // 64x64 tile + 8 pad
    __shared__ __bf16 Bs[64][72];
    __shared__ float t1A[64], t1B[64];
    __shared__ float redf[4];

    const int b = blockIdx.x;
    const int tid = threadIdx.x;
    const int w = tid >> 6, lane = tid & 63;

    const bool isCE = ((b & 1) == 0) && ((b >> 1) < CEB);
    if (isCE) {
        // ---------------- CE: online logsumexp, 1 row per wave x2 ----------
        const int blk = b >> 1;
        float wave_nll = 0.f;
#pragma unroll
        for (int r = 0; r < 2; ++r) {
            const int row = blk * 8 + w * 2 + r;
            const int t = targets[row];
            const float4* rp = reinterpret_cast<const float4*>(logits + (size_t)row * NC);
            const float xt = logits[(size_t)row * NC + t];
            float m = -3.4e38f, s = 0.f;
#pragma unroll
            for (int k = 0; k < 16; ++k) {               // 16 x 1KB coalesced
                float4 v = rp[lane + 64 * k];
                float mc = fmaxf(fmaxf(v.x, v.y), fmaxf(v.z, v.w));
                float mn = fmaxf(m, mc);
                s = s * __expf(m - mn)
                  + __expf(v.x - mn) + __expf(v.y - mn)
                  + __expf(v.z - mn) + __expf(v.w - mn);
                m = mn;
            }
#pragma unroll
            for (int off = 32; off; off >>= 1) {         // wave merge (m,s)
                float mo = __shfl_xor(m, off);
                float so = __shfl_xor(s, off);
                float mn = fmaxf(m, mo);
                s = s * __expf(m - mn) + so * __expf(mo - mn);
                m = mn;
            }
            wave_nll += m + __logf(s) - xt;
        }
        if (lane == 0) redf[w] = wave_nll;
        __syncthreads();
        if (tid == 0)
            nllp[blk] = (double)((redf[0] + redf[1]) + (redf[2] + redf[3]));
        return;
    }

    // ---------------- IC: 64x64 Gram tile, symmetric pair (bi<=bj) ---------
    const int icid = (b & 1) ? (b >> 1) : (2064 + ((b >> 1) - CEB));
    int u = icid, bi = 0;
    while (u >= NT64 - bi) { u -= NT64 - bi; ++bi; }
    const int bj = bi + u;
    const bool diag = (bi == bj);
    const int row0 = bi * 64, col0 = bj * 64;

    const int fr = lane & 15, fq = lane >> 4;
    const int wrow = (w >> 1) * 32, wcol = (w & 1) * 32;

    f32x4 acc[2][2];
#pragma unroll
    for (int mi = 0; mi < 2; ++mi)
#pragma unroll
        for (int nj = 0; nj < 2; ++nj) acc[mi][nj] = (f32x4){0.f, 0.f, 0.f, 0.f};

    float ssA[4], ssB[4];
#pragma unroll
    for (int i = 0; i < 4; ++i) { ssA[i] = 0.f; ssB[i] = 0.f; }

    for (int kt = 0; kt < ND / 64; ++kt) {
#pragma unroll
        for (int s2 = 0; s2 < 4; ++s2) {
            int c = tid + 256 * s2;          // 1024 float4 chunks per matrix
            int r = c >> 4, k4 = c & 15;
            float4 va = *reinterpret_cast<const float4*>(prot + (size_t)(row0 + r) * ND + kt * 64 + k4 * 4);
            ssA[s2] += va.x * va.x + va.y * va.y + va.z * va.z + va.w * va.w;
            ushort4 ha; ha.x = f2bf(va.x); ha.y = f2bf(va.y); ha.z = f2bf(va.z); ha.w = f2bf(va.w);
            *reinterpret_cast<ushort4*>(&As[r][k4 * 4]) = ha;
            float4 vb = *reinterpret_cast<const float4*>(prot + (size_t)(col0 + r) * ND + kt * 64 + k4 * 4);
            ssB[s2] += vb.x * vb.x + vb.y * vb.y + vb.z * vb.z + vb.w * vb.w;
            ushort4 hb; hb.x = f2bf(vb.x); hb.y = f2bf(vb.y); hb.z = f2bf(vb.z); hb.w = f2bf(vb.w);
            *reinterpret_cast<ushort4*>(&Bs[r][k4 * 4]) = hb;
        }
        __syncthreads();
#pragma unroll
        for (int ks = 0; ks < 64; ks += 32) {
            bf16x8 af[2], bfv[2];
#pragma unroll
            for (int mi = 0; mi < 2; ++mi)
                af[mi] = *reinterpret_cast<const bf16x8*>(&As[wrow + mi * 16 + fr][ks + fq * 8]);
#pragma unroll
            for (int nj = 0; nj < 2; ++nj)
                bfv[nj] = *reinterpret_cast<const bf16x8*>(&Bs[wcol + nj * 16 + fr][ks + fq * 8]);
#pragma unroll
            for (int mi = 0; mi < 2; ++mi)
#pragma unroll
                for (int nj = 0; nj < 2; ++nj)
                    acc[mi][nj] = __builtin_amdgcn_mfma_f32_16x16x32_bf16(af[mi], bfv[nj], acc[mi][nj], 0, 0, 0);
        }
        __syncthreads();
    }

    // per-row ||p||^2 (fp32, accumulated during staging) -> t1 in LDS
#pragma unroll
    for (int s2 = 0; s2 < 4; ++s2) {
        float a = ssA[s2], c2 = ssB[s2];
#pragma unroll
        for (int off = 1; off < 16; off <<= 1) {
            a  += __shfl_xor(a, off);
            c2 += __shfl_xor(c2, off);
        }
        if ((tid & 15) == 0) {
            int r = (tid >> 4) + 16 * s2;
            t1A[r] = (1.f - bnd[row0 + r]) * a;
            t1B[r] = (1.f - bnd[col0 + r]) * c2;
        }
    }
    __syncthreads();

    // epilogue: tij = t1[i] + (b_j-1)*G ; off-diag pairs also add the mirror
    float sum = 0.f;
#pragma unroll
    for (int mi = 0; mi < 2; ++mi) {
#pragma unroll
        for (int nj = 0; nj < 2; ++nj) {
            int jl = wcol + nj * 16 + fr;
            float t1b = t1B[jl];
            float bb1 = bnd[col0 + jl] - 1.f;
#pragma unroll
            for (int e = 0; e < 4; ++e) {
                int il = wrow + mi * 16 + fq * 4 + e;
                float G = acc[mi][nj][e];
                float tij = t1A[il] + bb1 * G;             // (i in A, j in B)
                if (diag) {
                    if (il != jl) sum += fmaxf(tij, 0.f);
                } else {
                    float tji = t1b + (bnd[row0 + il] - 1.f) * G;  // mirror
                    sum += fmaxf(tij, 0.f) + fmaxf(tji, 0.f);
                }
            }
        }
    }
#pragma unroll
    for (int off = 32; off; off >>= 1) sum += __shfl_xor(sum, off);
    if (lane == 0) redf[w] = sum;
    __syncthreads();
    if (tid == 0) icp[icid] = redf[0] + redf[1] + redf[2] + redf[3];
}

// ---------------- finalize: deterministic ordered reduction ----------------
__global__ __launch_bounds__(1024) void fin_kernel(const double* __restrict__ nllp,
                                                   const float* __restrict__ icp,
                                                   float* __restrict__ out) {
    int tid = threadIdx.x;
    double s = nllp[tid] + nllp[tid + 1024];                       // 2048
    double s2 = (double)icp[tid] + (double)icp[tid + 1024];        // 2080
    if (tid < 32) s2 += (double)icp[2048 + tid];
#pragma unroll
    for (int off = 32; off; off >>= 1) {
        s  += __shfl_xor(s, off);
        s2 += __shfl_xor(s2, off);
    }
    __shared__ double sm[16], sm2[16];
    int w = tid >> 6, lane = tid & 63;
    if (lane == 0) { sm[w] = s; sm2[w] = s2; }
    __syncthreads();
    if (tid == 0) {
        double a = 0.0, c = 0.0;
        for (int i = 0; i < 16; ++i) { a += sm[i]; c += sm2[i]; }
        double cls = a / (double)NB;
        double ic  = c / ((double)NC * (double)(NC - 1));
        out[0] = (float)(cls + 0.05 * ic);
        out[1] = (float)cls;
        out[2] = (float)ic;
    }
}

extern "C" void kernel_launch(void* const* d_in, const int* in_sizes, int n_in,
                              void* d_out, int out_size, void* d_ws, size_t ws_size,
                              hipStream_t stream) {
    const float* logits  = (const float*)d_in[0];
    const int*   targets = (const int*)d_in[1];
    const float* prot    = (const float*)d_in[2];
    const float* bnd     = (const float*)d_in[3];
    float* out = (float*)d_out;
    char* ws = (char*)d_ws;
    double* nllp = (double*)(ws + 0);
    float* icp = (float*)(ws + WS_ICP);

    fused_kernel<<<GRID, 256, 0, stream>>>(logits, targets, prot, bnd, nllp, icp);
    fin_kernel<<<1, 1024, 0, stream>>>(nllp, icp, out);
}